// Round 2
// baseline (549.138 us; speedup 1.0000x reference)
//
#include <hip/hip_runtime.h>

typedef __attribute__((ext_vector_type(8))) short bf16x8;
typedef __attribute__((ext_vector_type(4))) float f32x4;
typedef __attribute__((ext_vector_type(4))) unsigned short u16x4;
typedef unsigned short ushort_t;
typedef unsigned int uint32;

constexpr int B_ = 2, S_ = 2048, D_ = 1024, H_ = 16, DH_ = 64;
constexpr int M_TOK = B_ * S_;    // 4096
constexpr int N_QKV = 3 * D_;     // 3072

#define DEV __device__ __forceinline__

DEV ushort_t f2bf(float f) {
  uint32 u = __builtin_bit_cast(uint32, f);
  u += 0x7fffu + ((u >> 16) & 1u);
  return (ushort_t)(u >> 16);
}

DEV void gll16(const void* g, void* l) {
  __builtin_amdgcn_global_load_lds(
      (const __attribute__((address_space(1))) void*)g,
      (__attribute__((address_space(3))) void*)l, 16, 0, 0);
}

// ---------------- K0a: Q fp32 -> bf16 ----------------
__global__ __launch_bounds__(256) void k_cvt_q(const float* __restrict__ in,
                                               ushort_t* __restrict__ out) {
  int i = (blockIdx.x * 256 + threadIdx.x) * 4;
  float4 v = *(const float4*)(in + i);
  u16x4 o;
  o.x = f2bf(v.x); o.y = f2bf(v.y); o.z = f2bf(v.z); o.w = f2bf(v.w);
  *(u16x4*)(out + i) = o;
}

// ---------------- K0b: transpose + convert W [R][C] fp32 -> [C][R] bf16 ----
__global__ __launch_bounds__(256) void k_transpose_cvt(const float* __restrict__ in,
                                                       ushort_t* __restrict__ out,
                                                       int R, int C) {
  __shared__ float t[32][33];
  int bx = blockIdx.x, by = blockIdx.y;
  int tx = threadIdx.x & 31, ty = threadIdx.x >> 5;  // ty 0..7
#pragma unroll
  for (int i = 0; i < 4; ++i) {
    int r = by * 32 + ty + i * 8;
    t[ty + i * 8][tx] = in[(size_t)r * C + bx * 32 + tx];
  }
  __syncthreads();
#pragma unroll
  for (int i = 0; i < 4; ++i) {
    int orow = bx * 32 + ty + i * 8;  // output row = original col
    int ocol = by * 32 + tx;          // output col = original row
    out[(size_t)orow * R + ocol] = f2bf(t[tx][ty + i * 8]);
  }
}

// ---------------- K1: QKV GEMM (bf16 MFMA) + scatter epilogue -------------
__global__ __launch_bounds__(256) void k_gemm_qkv(
    const ushort_t* __restrict__ A,   // [4096][1024]
    const ushort_t* __restrict__ Bt,  // [3072][1024]
    const float* __restrict__ bias,   // [3072]
    ushort_t* __restrict__ qh,        // [B][H][S][64]
    ushort_t* __restrict__ kh,        // [B][H][S][64]
    ushort_t* __restrict__ vT) {      // [B][H][64][S]
  constexpr int K = 1024;
  __shared__ ushort_t lA[128 * 32];
  __shared__ ushort_t lB[128 * 32];
  const int t = threadIdx.x, lane = t & 63, w = t >> 6;
  const int wm = w >> 1, wn = w & 1;
  const int bm = blockIdx.x & 31, bn = blockIdx.x >> 5;  // 32 x 24

  f32x4 acc[4][4];
#pragma unroll
  for (int i = 0; i < 4; ++i)
#pragma unroll
    for (int j = 0; j < 4; ++j) acc[i][j] = f32x4{0.f, 0.f, 0.f, 0.f};

  const int srow = t >> 2;        // 0..63
  const int scol = (t & 3) * 8;   // 0,8,16,24
  for (int k0 = 0; k0 < K; k0 += 32) {
    __syncthreads();
    gll16(A + (size_t)(bm * 128 + srow) * K + k0 + scol, lA + srow * 32 + scol);
    gll16(A + (size_t)(bm * 128 + 64 + srow) * K + k0 + scol, lA + (64 + srow) * 32 + scol);
    gll16(Bt + (size_t)(bn * 128 + srow) * K + k0 + scol, lB + srow * 32 + scol);
    gll16(Bt + (size_t)(bn * 128 + 64 + srow) * K + k0 + scol, lB + (64 + srow) * 32 + scol);
    asm volatile("s_waitcnt vmcnt(0)" ::: "memory");
    __syncthreads();
    bf16x8 af[4], bfr[4];
#pragma unroll
    for (int i = 0; i < 4; ++i)
      af[i] = *(const bf16x8*)(lA + (wm * 64 + i * 16 + (lane & 15)) * 32 + (lane >> 4) * 8);
#pragma unroll
    for (int j = 0; j < 4; ++j)
      bfr[j] = *(const bf16x8*)(lB + (wn * 64 + j * 16 + (lane & 15)) * 32 + (lane >> 4) * 8);
#pragma unroll
    for (int i = 0; i < 4; ++i)
#pragma unroll
      for (int j = 0; j < 4; ++j)
        acc[i][j] = __builtin_amdgcn_mfma_f32_16x16x32_bf16(af[i], bfr[j], acc[i][j], 0, 0, 0);
  }
#pragma unroll
  for (int i = 0; i < 4; ++i) {
#pragma unroll
    for (int j = 0; j < 4; ++j) {
#pragma unroll
      for (int p = 0; p < 4; ++p) {
        int row = bm * 128 + wm * 64 + i * 16 + (lane >> 4) * 4 + p;  // token
        int col = bn * 128 + wn * 64 + j * 16 + (lane & 15);          // 0..3071
        float v = acc[i][j][p] + bias[col];
        ushort_t bv = f2bf(v);
        int b = row >> 11, s = row & (S_ - 1);
        int h = col / 192, r = col - h * 192;
        size_t bh = (size_t)(b * H_ + h);
        if (r < 64)
          qh[(bh * S_ + s) * 64 + r] = bv;
        else if (r < 128)
          kh[(bh * S_ + s) * 64 + (r - 64)] = bv;
        else
          vT[(bh * 64 + (r - 128)) * S_ + s] = bv;
      }
    }
  }
}

// ---------------- K23: fused scores(+write) + online softmax + PV ---------
// grid: 1024 blocks = 32 row-tiles x 32 bh; 4 waves/block, 16 q-rows/wave.
// Barrier-free: K/V/Q read direct from global (L2-resident slices), P goes
// through a per-wave XOR-swizzled LDS tile to convert C-layout -> A-frag.
__global__ __launch_bounds__(256) void k_fused_attn(
    const ushort_t* __restrict__ qh,  // [BH][S][64]
    const ushort_t* __restrict__ kh,  // [BH][S][64]
    const ushort_t* __restrict__ vT,  // [BH][64][S]
    const float* __restrict__ prev,   // [BH][S][S]
    float* __restrict__ scores,       // [BH][S][S]
    ushort_t* __restrict__ ctx) {     // [M_TOK][D]
  __shared__ ushort_t Plds[4][16 * 128];  // 4 KB per wave, XOR-swizzled
  const int t = threadIdx.x, lane = t & 63, w = t >> 6;
  const int rt = blockIdx.x & 31, bh = blockIdx.x >> 5;
  const int row0 = rt * 64 + w * 16;  // wave's q rows [row0, row0+16)
  const int lo = lane & 15, hi = lane >> 4;

  const ushort_t* qb = qh + ((size_t)bh * S_ + row0) * 64;
  const ushort_t* kb = kh + (size_t)bh * S_ * 64;
  const ushort_t* vb = vT + (size_t)bh * 64 * S_;
  const float* pb = prev + (size_t)bh * S_ * S_ + (size_t)(row0 + lo) * S_;
  float* sb = scores + (size_t)bh * S_ * S_ + (size_t)(row0 + lo) * S_;

  // Q B-fragments, direct from global: B[q=lo][d = dc*32 + hi*8 + j]
  bf16x8 qf[2];
  qf[0] = *(const bf16x8*)(qb + lo * 64 + hi * 8);
  qf[1] = *(const bf16x8*)(qb + lo * 64 + 32 + hi * 8);

  char* pw = (char*)&Plds[w][0];
  const int swz = (lo & 7) << 4;  // XOR on byte addr, per-row

  f32x4 acco[4];
#pragma unroll
  for (int dn = 0; dn < 4; ++dn) acco[dn] = f32x4{0.f, 0.f, 0.f, 0.f};
  float m_run = -1e30f, l_run = 0.f;

  for (int kt = 0; kt < S_; kt += 128) {
    // ---- swapped QK^T: lane holds S[q=lo][k = kf*16 + hi*4 + p] ----
    f32x4 acc[8];
#pragma unroll
    for (int kf = 0; kf < 8; ++kf) acc[kf] = f32x4{0.f, 0.f, 0.f, 0.f};
#pragma unroll
    for (int kf = 0; kf < 8; ++kf) {
      const ushort_t* kr = kb + (size_t)(kt + kf * 16 + lo) * 64 + hi * 8;
      bf16x8 k0 = *(const bf16x8*)(kr);
      bf16x8 k1 = *(const bf16x8*)(kr + 32);
      acc[kf] = __builtin_amdgcn_mfma_f32_16x16x32_bf16(k0, qf[0], acc[kf], 0, 0, 0);
      acc[kf] = __builtin_amdgcn_mfma_f32_16x16x32_bf16(k1, qf[1], acc[kf], 0, 0, 0);
    }
    // ---- scale + prev; write scores (store-and-forget) ----
    float tmax = -1e30f;
#pragma unroll
    for (int kf = 0; kf < 8; ++kf) {
      float4 pv = *(const float4*)(pb + kt + kf * 16 + hi * 4);
      acc[kf][0] = acc[kf][0] * 0.125f + pv.x;
      acc[kf][1] = acc[kf][1] * 0.125f + pv.y;
      acc[kf][2] = acc[kf][2] * 0.125f + pv.z;
      acc[kf][3] = acc[kf][3] * 0.125f + pv.w;
      *(float4*)(sb + kt + kf * 16 + hi * 4) =
          float4{acc[kf][0], acc[kf][1], acc[kf][2], acc[kf][3]};
      tmax = fmaxf(tmax, fmaxf(fmaxf(acc[kf][0], acc[kf][1]), fmaxf(acc[kf][2], acc[kf][3])));
    }
    // ---- online softmax (row = lo; data spread over 4 hi-lanes) ----
    tmax = fmaxf(tmax, __shfl_xor(tmax, 16));
    tmax = fmaxf(tmax, __shfl_xor(tmax, 32));
    float m_new = fmaxf(m_run, tmax);
    float fs = __expf(m_run - m_new);
    m_run = m_new;
    float lsum = 0.f;
#pragma unroll
    for (int kf = 0; kf < 8; ++kf) {
      float e0 = __expf(acc[kf][0] - m_new);
      float e1 = __expf(acc[kf][1] - m_new);
      float e2 = __expf(acc[kf][2] - m_new);
      float e3 = __expf(acc[kf][3] - m_new);
      lsum += (e0 + e1) + (e2 + e3);
      u16x4 pk;
      pk.x = f2bf(e0); pk.y = f2bf(e1); pk.z = f2bf(e2); pk.w = f2bf(e3);
      int byte = (lo * 256 + (kf * 16 + hi * 4) * 2) ^ swz;
      *(u16x4*)(pw + byte) = pk;
    }
    lsum += __shfl_xor(lsum, 16);
    lsum += __shfl_xor(lsum, 32);
    l_run = l_run * fs + lsum;
    // rescale O: acco rows are q = hi*4 + p -> fetch that row's fs
    float fr[4];
#pragma unroll
    for (int p = 0; p < 4; ++p) fr[p] = __shfl(fs, hi * 4 + p);
#pragma unroll
    for (int dn = 0; dn < 4; ++dn)
#pragma unroll
      for (int p = 0; p < 4; ++p) acco[dn][p] *= fr[p];
    // ---- PV: A = P from swizzled LDS, B = vT rows (d-major) ----
#pragma unroll
    for (int kc = 0; kc < 4; ++kc) {
      int byte = (lo * 256 + kc * 64 + hi * 16) ^ swz;
      bf16x8 pa = *(const bf16x8*)(pw + byte);
#pragma unroll
      for (int dn = 0; dn < 4; ++dn) {
        bf16x8 vf = *(const bf16x8*)(vb + (size_t)(dn * 16 + lo) * S_ + kt + kc * 32 + hi * 8);
        acco[dn] = __builtin_amdgcn_mfma_f32_16x16x32_bf16(pa, vf, acco[dn], 0, 0, 0);
      }
    }
  }
  // ---- normalize + store ctx bf16 ----
  float inv[4];
#pragma unroll
  for (int p = 0; p < 4; ++p) inv[p] = 1.0f / __shfl(l_run, hi * 4 + p);
  const int b = bh >> 4, h = bh & 15;
#pragma unroll
  for (int dn = 0; dn < 4; ++dn) {
#pragma unroll
    for (int p = 0; p < 4; ++p) {
      int q = row0 + hi * 4 + p;
      ctx[(size_t)(b * S_ + q) * D_ + h * 64 + dn * 16 + lo] = f2bf(acco[dn][p] * inv[p]);
    }
  }
}

// ---------------- K4: output GEMM + bias (fp32 out) -----------------------
__global__ __launch_bounds__(256) void k_gemm_out(
    const ushort_t* __restrict__ A,   // ctx [4096][1024]
    const ushort_t* __restrict__ Bt,  // WoutT [1024][1024]
    const float* __restrict__ bias,   // [1024]
    float* __restrict__ out) {
  constexpr int K = 1024;
  __shared__ ushort_t lA[128 * 32];
  __shared__ ushort_t lB[128 * 32];
  const int t = threadIdx.x, lane = t & 63, w = t >> 6;
  const int wm = w >> 1, wn = w & 1;
  const int bm = blockIdx.x & 31, bn = blockIdx.x >> 5;  // 32 x 8

  f32x4 acc[4][4];
#pragma unroll
  for (int i = 0; i < 4; ++i)
#pragma unroll
    for (int j = 0; j < 4; ++j) acc[i][j] = f32x4{0.f, 0.f, 0.f, 0.f};

  const int srow = t >> 2;
  const int scol = (t & 3) * 8;
  for (int k0 = 0; k0 < K; k0 += 32) {
    __syncthreads();
    gll16(A + (size_t)(bm * 128 + srow) * K + k0 + scol, lA + srow * 32 + scol);
    gll16(A + (size_t)(bm * 128 + 64 + srow) * K + k0 + scol, lA + (64 + srow) * 32 + scol);
    gll16(Bt + (size_t)(bn * 128 + srow) * K + k0 + scol, lB + srow * 32 + scol);
    gll16(Bt + (size_t)(bn * 128 + 64 + srow) * K + k0 + scol, lB + (64 + srow) * 32 + scol);
    asm volatile("s_waitcnt vmcnt(0)" ::: "memory");
    __syncthreads();
    bf16x8 af[4], bfr[4];
#pragma unroll
    for (int i = 0; i < 4; ++i)
      af[i] = *(const bf16x8*)(lA + (wm * 64 + i * 16 + (lane & 15)) * 32 + (lane >> 4) * 8);
#pragma unroll
    for (int j = 0; j < 4; ++j)
      bfr[j] = *(const bf16x8*)(lB + (wn * 64 + j * 16 + (lane & 15)) * 32 + (lane >> 4) * 8);
#pragma unroll
    for (int i = 0; i < 4; ++i)
#pragma unroll
      for (int j = 0; j < 4; ++j)
        acc[i][j] = __builtin_amdgcn_mfma_f32_16x16x32_bf16(af[i], bfr[j], acc[i][j], 0, 0, 0);
  }
#pragma unroll
  for (int i = 0; i < 4; ++i) {
#pragma unroll
    for (int j = 0; j < 4; ++j) {
#pragma unroll
      for (int p = 0; p < 4; ++p) {
        int row = bm * 128 + wm * 64 + i * 16 + (lane >> 4) * 4 + p;
        int col = bn * 128 + wn * 64 + j * 16 + (lane & 15);
        out[(size_t)row * 1024 + col] = acc[i][j][p] + bias[col];
      }
    }
  }
}

extern "C" void kernel_launch(void* const* d_in, const int* in_sizes, int n_in,
                              void* d_out, int out_size, void* d_ws, size_t ws_size,
                              hipStream_t stream) {
  (void)in_sizes; (void)n_in; (void)out_size; (void)ws_size;
  const float* Q     = (const float*)d_in[0];
  const float* prev  = (const float*)d_in[1];
  const float* W_qkv = (const float*)d_in[2];
  const float* b_qkv = (const float*)d_in[3];
  const float* W_out = (const float*)d_in[4];
  const float* b_out = (const float*)d_in[5];
  float* out = (float*)d_out;
  float* scores_out = out + (size_t)M_TOK * D_;  // output first, then scores

  char* ws = (char*)d_ws;
  ushort_t* Qb    = (ushort_t*)(ws + (size_t)0);          // 8 MB
  ushort_t* WqkvT = (ushort_t*)(ws + ((size_t)8  << 20)); // 6 MB
  ushort_t* WoutT = (ushort_t*)(ws + ((size_t)14 << 20)); // 2 MB
  ushort_t* qh    = (ushort_t*)(ws + ((size_t)16 << 20)); // 8 MB
  ushort_t* kh    = (ushort_t*)(ws + ((size_t)24 << 20)); // 8 MB
  ushort_t* vT    = (ushort_t*)(ws + ((size_t)32 << 20)); // 8 MB
  ushort_t* ctx   = (ushort_t*)(ws + ((size_t)40 << 20)); // 8 MB  => 48 MB total

  k_cvt_q<<<4096, 256, 0, stream>>>(Q, Qb);
  k_transpose_cvt<<<dim3(96, 32), 256, 0, stream>>>(W_qkv, WqkvT, 1024, 3072);
  k_transpose_cvt<<<dim3(32, 32), 256, 0, stream>>>(W_out, WoutT, 1024, 1024);
  k_gemm_qkv<<<768, 256, 0, stream>>>(Qb, WqkvT, b_qkv, qh, kh, vT);
  k_fused_attn<<<1024, 256, 0, stream>>>(qh, kh, vT, prev, scores_out, ctx);
  k_gemm_out<<<256, 256, 0, stream>>>(ctx, WoutT, b_out, out);
}

// Round 3
// 527.447 us; speedup vs baseline: 1.0411x; 1.0411x over previous
//
#include <hip/hip_runtime.h>

typedef __attribute__((ext_vector_type(8))) short bf16x8;
typedef __attribute__((ext_vector_type(4))) float f32x4;
typedef __attribute__((ext_vector_type(4))) unsigned short u16x4;
typedef unsigned short ushort_t;
typedef unsigned int uint32;

constexpr int B_ = 2, S_ = 2048, D_ = 1024, H_ = 16, DH_ = 64;
constexpr int M_TOK = B_ * S_;    // 4096
constexpr int N_QKV = 3 * D_;     // 3072

#define DEV __device__ __forceinline__

DEV ushort_t f2bf(float f) {
  uint32 u = __builtin_bit_cast(uint32, f);
  u += 0x7fffu + ((u >> 16) & 1u);
  return (ushort_t)(u >> 16);
}

DEV void gll16(const void* g, void* l) {
  __builtin_amdgcn_global_load_lds(
      (const __attribute__((address_space(1))) void*)g,
      (__attribute__((address_space(3))) void*)l, 16, 0, 0);
}

// ---------------- K0a: Q fp32 -> bf16 ----------------
__global__ __launch_bounds__(256) void k_cvt_q(const float* __restrict__ in,
                                               ushort_t* __restrict__ out) {
  int i = (blockIdx.x * 256 + threadIdx.x) * 4;
  float4 v = *(const float4*)(in + i);
  u16x4 o;
  o.x = f2bf(v.x); o.y = f2bf(v.y); o.z = f2bf(v.z); o.w = f2bf(v.w);
  *(u16x4*)(out + i) = o;
}

// ---------------- K0b: transpose + convert W [R][C] fp32 -> [C][R] bf16 ----
__global__ __launch_bounds__(256) void k_transpose_cvt(const float* __restrict__ in,
                                                       ushort_t* __restrict__ out,
                                                       int R, int C) {
  __shared__ float t[32][33];
  int bx = blockIdx.x, by = blockIdx.y;
  int tx = threadIdx.x & 31, ty = threadIdx.x >> 5;  // ty 0..7
#pragma unroll
  for (int i = 0; i < 4; ++i) {
    int r = by * 32 + ty + i * 8;
    t[ty + i * 8][tx] = in[(size_t)r * C + bx * 32 + tx];
  }
  __syncthreads();
#pragma unroll
  for (int i = 0; i < 4; ++i) {
    int orow = bx * 32 + ty + i * 8;  // output row = original col
    int ocol = by * 32 + tx;          // output col = original row
    out[(size_t)orow * R + ocol] = f2bf(t[tx][ty + i * 8]);
  }
}

// ---------------- K1: QKV GEMM (bf16 MFMA) + scatter epilogue -------------
__global__ __launch_bounds__(256) void k_gemm_qkv(
    const ushort_t* __restrict__ A,   // [4096][1024]
    const ushort_t* __restrict__ Bt,  // [3072][1024]
    const float* __restrict__ bias,   // [3072]
    ushort_t* __restrict__ qh,        // [B][H][S][64]
    ushort_t* __restrict__ kh,        // [B][H][S][64]
    ushort_t* __restrict__ vT) {      // [B][H][64][S]
  constexpr int K = 1024;
  __shared__ ushort_t lA[128 * 32];
  __shared__ ushort_t lB[128 * 32];
  const int t = threadIdx.x, lane = t & 63, w = t >> 6;
  const int wm = w >> 1, wn = w & 1;
  const int bm = blockIdx.x & 31, bn = blockIdx.x >> 5;  // 32 x 24

  f32x4 acc[4][4];
#pragma unroll
  for (int i = 0; i < 4; ++i)
#pragma unroll
    for (int j = 0; j < 4; ++j) acc[i][j] = f32x4{0.f, 0.f, 0.f, 0.f};

  const int srow = t >> 2;        // 0..63
  const int scol = (t & 3) * 8;   // 0,8,16,24
  for (int k0 = 0; k0 < K; k0 += 32) {
    __syncthreads();
    gll16(A + (size_t)(bm * 128 + srow) * K + k0 + scol, lA + srow * 32 + scol);
    gll16(A + (size_t)(bm * 128 + 64 + srow) * K + k0 + scol, lA + (64 + srow) * 32 + scol);
    gll16(Bt + (size_t)(bn * 128 + srow) * K + k0 + scol, lB + srow * 32 + scol);
    gll16(Bt + (size_t)(bn * 128 + 64 + srow) * K + k0 + scol, lB + (64 + srow) * 32 + scol);
    asm volatile("s_waitcnt vmcnt(0)" ::: "memory");
    __syncthreads();
    bf16x8 af[4], bfr[4];
#pragma unroll
    for (int i = 0; i < 4; ++i)
      af[i] = *(const bf16x8*)(lA + (wm * 64 + i * 16 + (lane & 15)) * 32 + (lane >> 4) * 8);
#pragma unroll
    for (int j = 0; j < 4; ++j)
      bfr[j] = *(const bf16x8*)(lB + (wn * 64 + j * 16 + (lane & 15)) * 32 + (lane >> 4) * 8);
#pragma unroll
    for (int i = 0; i < 4; ++i)
#pragma unroll
      for (int j = 0; j < 4; ++j)
        acc[i][j] = __builtin_amdgcn_mfma_f32_16x16x32_bf16(af[i], bfr[j], acc[i][j], 0, 0, 0);
  }
#pragma unroll
  for (int i = 0; i < 4; ++i) {
#pragma unroll
    for (int j = 0; j < 4; ++j) {
#pragma unroll
      for (int p = 0; p < 4; ++p) {
        int row = bm * 128 + wm * 64 + i * 16 + (lane >> 4) * 4 + p;  // token
        int col = bn * 128 + wn * 64 + j * 16 + (lane & 15);          // 0..3071
        float v = acc[i][j][p] + bias[col];
        ushort_t bv = f2bf(v);
        int b = row >> 11, s = row & (S_ - 1);
        int h = col / 192, r = col - h * 192;
        size_t bh = (size_t)(b * H_ + h);
        if (r < 64)
          qh[(bh * S_ + s) * 64 + r] = bv;
        else if (r < 128)
          kh[(bh * S_ + s) * 64 + (r - 64)] = bv;
        else
          vT[(bh * 64 + (r - 128)) * S_ + s] = bv;
      }
    }
  }
}

// ---------------- K23: fused scores + online softmax + PV, split-K x2 -----
// Block: 256 thr = 4 waves = 2 q-groups (16 rows each) x 2 k-halves.
// Grid: 2048 = 32 bh x 64 row-tiles, XCD-clustered (each XCD owns 4 heads).
// PV is operand-swapped so O lives in [d][q=lo] layout: softmax state and
// rescale factors are lane-local (no shuffles in the chain). prev is
// double-buffered in registers one kt-tile ahead.
__global__ __launch_bounds__(256, 3) void k_fused_attn(
    const ushort_t* __restrict__ qhp,  // [BH][S][64]
    const ushort_t* __restrict__ khp,  // [BH][S][64]
    const ushort_t* __restrict__ vT,   // [BH][64][S]
    const float* __restrict__ prev,    // [BH][S][S]
    float* __restrict__ scores,        // [BH][S][S]
    ushort_t* __restrict__ ctx) {      // [M_TOK][D]
  __shared__ ushort_t Plds[4][2048];   // per-wave P tile, XOR-swizzled (4KB)
  __shared__ float Obuf[4][1024];      // merge: O partials [q=16][d=64]
  __shared__ float Ml[4][2][16];       // merge: m, l per row
  const int t = threadIdx.x, lane = t & 63, w = t >> 6;
  const int qg = w & 1, ks = w >> 1;
  const int d0 = blockIdx.x;
  const int xcd = d0 & 7, jj = d0 >> 3;
  const int bh = xcd * 4 + (jj >> 6), rt = jj & 63;
  const int row0 = rt * 32 + qg * 16;
  const int lo = lane & 15, hi = lane >> 4;
  const int kt0 = ks * 1024;

  const ushort_t* qb = qhp + ((size_t)bh * S_ + row0) * 64;
  const ushort_t* kb = khp + (size_t)bh * S_ * 64;
  const ushort_t* vb = vT + (size_t)bh * 64 * S_;
  const float* pb = prev + (size_t)bh * S_ * S_ + (size_t)(row0 + lo) * S_;
  float* sb = scores + (size_t)bh * S_ * S_ + (size_t)(row0 + lo) * S_;

  // Q B-fragments (q = lo)
  bf16x8 qf0 = *(const bf16x8*)(qb + lo * 64 + hi * 8);
  bf16x8 qf1 = *(const bf16x8*)(qb + lo * 64 + 32 + hi * 8);

  char* pw = (char*)&Plds[w][0];
  const int swz = (lo & 7) << 4;

  f32x4 acco[4];
#pragma unroll
  for (int dn = 0; dn < 4; ++dn) acco[dn] = f32x4{0.f, 0.f, 0.f, 0.f};
  float m_run = -1e30f, l_run = 0.f;

  // prev prefetch (double-buffered in regs)
  float4 pcur[8];
#pragma unroll
  for (int kf = 0; kf < 8; ++kf)
    pcur[kf] = *(const float4*)(pb + kt0 + kf * 16 + hi * 4);

  for (int it = 0; it < 8; ++it) {
    const int kt = kt0 + it * 128;
    float4 pnext[8];
    if (it < 7) {
#pragma unroll
      for (int kf = 0; kf < 8; ++kf)
        pnext[kf] = *(const float4*)(pb + kt + 128 + kf * 16 + hi * 4);
    }
    // ---- swapped QK^T: lane holds S[q=lo][k = kf*16 + hi*4 + p] ----
    f32x4 acc[8];
#pragma unroll
    for (int kf = 0; kf < 8; ++kf) acc[kf] = f32x4{0.f, 0.f, 0.f, 0.f};
#pragma unroll
    for (int kf = 0; kf < 8; ++kf) {
      const ushort_t* kr = kb + (size_t)(kt + kf * 16 + lo) * 64 + hi * 8;
      bf16x8 k0 = *(const bf16x8*)(kr);
      bf16x8 k1 = *(const bf16x8*)(kr + 32);
      acc[kf] = __builtin_amdgcn_mfma_f32_16x16x32_bf16(k0, qf0, acc[kf], 0, 0, 0);
      acc[kf] = __builtin_amdgcn_mfma_f32_16x16x32_bf16(k1, qf1, acc[kf], 0, 0, 0);
    }
    // ---- scale + prev; write scores; row max ----
    float tmax = -1e30f;
#pragma unroll
    for (int kf = 0; kf < 8; ++kf) {
      acc[kf][0] = acc[kf][0] * 0.125f + pcur[kf].x;
      acc[kf][1] = acc[kf][1] * 0.125f + pcur[kf].y;
      acc[kf][2] = acc[kf][2] * 0.125f + pcur[kf].z;
      acc[kf][3] = acc[kf][3] * 0.125f + pcur[kf].w;
      *(float4*)(sb + kt + kf * 16 + hi * 4) =
          float4{acc[kf][0], acc[kf][1], acc[kf][2], acc[kf][3]};
      tmax = fmaxf(tmax, fmaxf(fmaxf(acc[kf][0], acc[kf][1]), fmaxf(acc[kf][2], acc[kf][3])));
    }
    tmax = fmaxf(tmax, __shfl_xor(tmax, 16));
    tmax = fmaxf(tmax, __shfl_xor(tmax, 32));
    float m_new = fmaxf(m_run, tmax);
    float fs = __expf(m_run - m_new);
    m_run = m_new;
    float lsum = 0.f;
#pragma unroll
    for (int kf = 0; kf < 8; ++kf) {
      float e0 = __expf(acc[kf][0] - m_new);
      float e1 = __expf(acc[kf][1] - m_new);
      float e2 = __expf(acc[kf][2] - m_new);
      float e3 = __expf(acc[kf][3] - m_new);
      lsum += (e0 + e1) + (e2 + e3);
      u16x4 pk;
      pk.x = f2bf(e0); pk.y = f2bf(e1); pk.z = f2bf(e2); pk.w = f2bf(e3);
      int byte = (lo * 256 + kf * 32 + hi * 8) ^ swz;
      *(u16x4*)(pw + byte) = pk;
    }
    lsum += __shfl_xor(lsum, 16);
    lsum += __shfl_xor(lsum, 32);
    l_run = l_run * fs + lsum;
    // rescale O (q = lo -> lane-local factor, no shuffles)
#pragma unroll
    for (int dn = 0; dn < 4; ++dn)
#pragma unroll
      for (int p = 0; p < 4; ++p) acco[dn][p] *= fs;
    // ---- PV (operand-swapped): A = vT rows (d=lo), B = P (q=lo) ----
#pragma unroll
    for (int kc = 0; kc < 4; ++kc) {
      int byte = (lo * 256 + kc * 64 + hi * 16) ^ swz;
      bf16x8 pa = *(const bf16x8*)(pw + byte);
#pragma unroll
      for (int dn = 0; dn < 4; ++dn) {
        bf16x8 vf = *(const bf16x8*)(vb + (size_t)(dn * 16 + lo) * S_ + kt + kc * 32 + hi * 8);
        acco[dn] = __builtin_amdgcn_mfma_f32_16x16x32_bf16(vf, pa, acco[dn], 0, 0, 0);
      }
    }
    if (it < 7) {
#pragma unroll
      for (int kf = 0; kf < 8; ++kf) pcur[kf] = pnext[kf];
    }
  }

  // ---- split-K merge: exchange partials via LDS ----
#pragma unroll
  for (int dn = 0; dn < 4; ++dn)
    *(f32x4*)&Obuf[w][lo * 64 + dn * 16 + hi * 4] = acco[dn];
  if (hi == 0) { Ml[w][0][lo] = m_run; Ml[w][1][lo] = l_run; }
  __syncthreads();
  if (w < 2) {
    const int pwave = w + 2;
    float m2 = Ml[pwave][0][lo], l2 = Ml[pwave][1][lo];
    float mm = fmaxf(m_run, m2);
    float a1 = __expf(m_run - mm), a2 = __expf(m2 - mm);
    float inv = 1.0f / (l_run * a1 + l2 * a2);
    const int b = bh >> 4, h = bh & 15;
#pragma unroll
    for (int dn = 0; dn < 4; ++dn) {
      f32x4 o2 = *(const f32x4*)&Obuf[pwave][lo * 64 + dn * 16 + hi * 4];
      u16x4 ov;
#pragma unroll
      for (int p = 0; p < 4; ++p)
        ov[p] = f2bf((acco[dn][p] * a1 + o2[p] * a2) * inv);
      *(u16x4*)(ctx + (size_t)(b * S_ + row0 + lo) * D_ + h * 64 + dn * 16 + hi * 4) = ov;
    }
  }
}

// ---------------- K4: output GEMM + bias (fp32 out) -----------------------
__global__ __launch_bounds__(256) void k_gemm_out(
    const ushort_t* __restrict__ A,   // ctx [4096][1024]
    const ushort_t* __restrict__ Bt,  // WoutT [1024][1024]
    const float* __restrict__ bias,   // [1024]
    float* __restrict__ out) {
  constexpr int K = 1024;
  __shared__ ushort_t lA[128 * 32];
  __shared__ ushort_t lB[128 * 32];
  const int t = threadIdx.x, lane = t & 63, w = t >> 6;
  const int wm = w >> 1, wn = w & 1;
  const int bm = blockIdx.x & 31, bn = blockIdx.x >> 5;  // 32 x 8

  f32x4 acc[4][4];
#pragma unroll
  for (int i = 0; i < 4; ++i)
#pragma unroll
    for (int j = 0; j < 4; ++j) acc[i][j] = f32x4{0.f, 0.f, 0.f, 0.f};

  const int srow = t >> 2;
  const int scol = (t & 3) * 8;
  for (int k0 = 0; k0 < K; k0 += 32) {
    __syncthreads();
    gll16(A + (size_t)(bm * 128 + srow) * K + k0 + scol, lA + srow * 32 + scol);
    gll16(A + (size_t)(bm * 128 + 64 + srow) * K + k0 + scol, lA + (64 + srow) * 32 + scol);
    gll16(Bt + (size_t)(bn * 128 + srow) * K + k0 + scol, lB + srow * 32 + scol);
    gll16(Bt + (size_t)(bn * 128 + 64 + srow) * K + k0 + scol, lB + (64 + srow) * 32 + scol);
    asm volatile("s_waitcnt vmcnt(0)" ::: "memory");
    __syncthreads();
    bf16x8 af[4], bfr[4];
#pragma unroll
    for (int i = 0; i < 4; ++i)
      af[i] = *(const bf16x8*)(lA + (wm * 64 + i * 16 + (lane & 15)) * 32 + (lane >> 4) * 8);
#pragma unroll
    for (int j = 0; j < 4; ++j)
      bfr[j] = *(const bf16x8*)(lB + (wn * 64 + j * 16 + (lane & 15)) * 32 + (lane >> 4) * 8);
#pragma unroll
    for (int i = 0; i < 4; ++i)
#pragma unroll
      for (int j = 0; j < 4; ++j)
        acc[i][j] = __builtin_amdgcn_mfma_f32_16x16x32_bf16(af[i], bfr[j], acc[i][j], 0, 0, 0);
  }
#pragma unroll
  for (int i = 0; i < 4; ++i) {
#pragma unroll
    for (int j = 0; j < 4; ++j) {
#pragma unroll
      for (int p = 0; p < 4; ++p) {
        int row = bm * 128 + wm * 64 + i * 16 + (lane >> 4) * 4 + p;
        int col = bn * 128 + wn * 64 + j * 16 + (lane & 15);
        out[(size_t)row * 1024 + col] = acc[i][j][p] + bias[col];
      }
    }
  }
}

extern "C" void kernel_launch(void* const* d_in, const int* in_sizes, int n_in,
                              void* d_out, int out_size, void* d_ws, size_t ws_size,
                              hipStream_t stream) {
  (void)in_sizes; (void)n_in; (void)out_size; (void)ws_size;
  const float* Q     = (const float*)d_in[0];
  const float* prev  = (const float*)d_in[1];
  const float* W_qkv = (const float*)d_in[2];
  const float* b_qkv = (const float*)d_in[3];
  const float* W_out = (const float*)d_in[4];
  const float* b_out = (const float*)d_in[5];
  float* out = (float*)d_out;
  float* scores_out = out + (size_t)M_TOK * D_;  // output first, then scores

  char* ws = (char*)d_ws;
  ushort_t* Qb    = (ushort_t*)(ws + (size_t)0);          // 8 MB
  ushort_t* WqkvT = (ushort_t*)(ws + ((size_t)8  << 20)); // 6 MB
  ushort_t* WoutT = (ushort_t*)(ws + ((size_t)14 << 20)); // 2 MB
  ushort_t* qh    = (ushort_t*)(ws + ((size_t)16 << 20)); // 8 MB
  ushort_t* kh    = (ushort_t*)(ws + ((size_t)24 << 20)); // 8 MB
  ushort_t* vT    = (ushort_t*)(ws + ((size_t)32 << 20)); // 8 MB
  ushort_t* ctx   = (ushort_t*)(ws + ((size_t)40 << 20)); // 8 MB  => 48 MB total

  k_cvt_q<<<4096, 256, 0, stream>>>(Q, Qb);
  k_transpose_cvt<<<dim3(96, 32), 256, 0, stream>>>(W_qkv, WqkvT, 1024, 3072);
  k_transpose_cvt<<<dim3(32, 32), 256, 0, stream>>>(W_out, WoutT, 1024, 1024);
  k_gemm_qkv<<<768, 256, 0, stream>>>(Qb, WqkvT, b_qkv, qh, kh, vT);
  k_fused_attn<<<2048, 256, 0, stream>>>(qh, kh, vT, prev, scores_out, ctx);
  k_gemm_out<<<256, 256, 0, stream>>>(ctx, WoutT, b_out, out);
}